// Round 1
// baseline (82.675 us; speedup 1.0000x reference)
//
#include <hip/hip_runtime.h>
#include <math.h>

// SinenetLayerV3: per (s,b,m) row — harmonic sin/cos basis contracted with x,
// then [2K]->[D] matmul + bias + relu, concat relu(nlf).
//
// Restructure: deg[k][t] = k * theta_t, theta_t = 2*pi*f*(t*T_WAV - tau).
// One hw sincos per t (v_sin_f32/v_cos_f32 take REVOLUTIONS -> feed fract),
// then complex-rotation recurrence over k: z_{k+1} = z_k * e^{i theta}.

#define T_WAV_F (1.0f / 16000.0f)
#define LOG_F_MEAN_F 5.04418f
#define LOG_F_STD_F 0.358402f

constexpr int S = 16, B = 16, M = 20, T = 640, K = 16, D = 80;
constexpr int ROWS = S * B * M;       // 5120
constexpr int WPB = 4;                // waves per block (256 threads)
constexpr int TWO_K = 2 * K;          // 32
constexpr int W_STRIDE = TWO_K + 1;   // 33: pad -> bank = (d + j) % 32, conflict-free

__global__ __launch_bounds__(256) void sinenet_kernel(
    const float* __restrict__ x,    // [S,B,M,T]
    const float* __restrict__ nlf,  // [S,B,M]
    const float* __restrict__ tau,  // [S,B,M]
    const float* __restrict__ W,    // [D, 2K]
    const float* __restrict__ bias, // [D]
    float* __restrict__ out)        // [S,B, M*D + M]
{
    __shared__ float Wlds[D * W_STRIDE];
    __shared__ float blds[D];

    // cooperative stage of W (2560 f32) + bias into LDS (reused by all 4 waves)
    for (int i = threadIdx.x; i < D * TWO_K; i += 256) {
        Wlds[(i / TWO_K) * W_STRIDE + (i % TWO_K)] = W[i];
    }
    if (threadIdx.x < D) blds[threadIdx.x] = bias[threadIdx.x];
    __syncthreads();

    const int lane = threadIdx.x & 63;
    const int row  = blockIdx.x * WPB + (threadIdx.x >> 6);  // 0..5119, grid exact

    const float* __restrict__ xrow = x + (size_t)row * T;
    const float nlf_v = nlf[row];
    const float tau_v = tau[row];

    // f = exp(nlf*std + mean); phase in revolutions: rev(n) = f*(n*T_WAV - tau)
    const float f    = __expf(fmaf(nlf_v, LOG_F_STD_F, LOG_F_MEAN_F));
    const float drev = f * T_WAV_F;
    const float rev0 = -f * tau_v;

    float sacc[K], cacc[K];
    #pragma unroll
    for (int k = 0; k < K; ++k) { sacc[k] = 0.0f; cacc[k] = 0.0f; }

    #pragma unroll 2
    for (int it = 0; it < T / 64; ++it) {   // 10 iterations, coalesced stride-64
        const int n = lane + it * 64;
        const float xv = xrow[n];
        const float rev = fmaf((float)n, drev, rev0);
        const float fr  = rev - floorf(rev);      // [0,1) revolutions
        float s1, c1;
        asm("v_sin_f32 %0, %1" : "=v"(s1) : "v"(fr));  // sin(2*pi*fr)
        asm("v_cos_f32 %0, %1" : "=v"(c1) : "v"(fr));  // cos(2*pi*fr)
        float zr = c1, zi = s1;                    // z = e^{i theta}, k=1
        #pragma unroll
        for (int k = 0; k < K; ++k) {
            sacc[k] = fmaf(xv, zi, sacc[k]);
            cacc[k] = fmaf(xv, zr, cacc[k]);
            const float nzr = fmaf(zr, c1, -(zi * s1));
            const float nzi = fmaf(zr, s1,  (zi * c1));
            zr = nzr; zi = nzi;
        }
    }

    // butterfly reduce all 32 accumulators across the 64-lane wave
    #pragma unroll
    for (int k = 0; k < K; ++k) {
        #pragma unroll
        for (int off = 32; off > 0; off >>= 1) {
            sacc[k] += __shfl_xor(sacc[k], off, 64);
            cacc[k] += __shfl_xor(cacc[k], off, 64);
        }
    }

    // epilogue: y[d] = sum_k s_x[k]*W[d][k] + c_x[k]*W[d][K+k] + b[d]; relu; store
    const int sb = row / M;
    const int m  = row % M;
    float* __restrict__ orow = out + (size_t)sb * (M * D + M);

    #pragma unroll
    for (int pass = 0; pass < 2; ++pass) {
        const int d = lane + pass * 64;
        if (d < D) {
            const float* __restrict__ wr = &Wlds[d * W_STRIDE];
            float y = blds[d];
            #pragma unroll
            for (int k = 0; k < K; ++k) {
                y = fmaf(sacc[k], wr[k],     y);
                y = fmaf(cacc[k], wr[K + k], y);
            }
            orow[m * D + d] = fmaxf(y, 0.0f);
        }
    }
    if (lane == 0) orow[M * D + m] = fmaxf(nlf_v, 0.0f);
}

extern "C" void kernel_launch(void* const* d_in, const int* in_sizes, int n_in,
                              void* d_out, int out_size, void* d_ws, size_t ws_size,
                              hipStream_t stream) {
    const float* x    = (const float*)d_in[0];
    const float* nlf  = (const float*)d_in[1];
    const float* tau  = (const float*)d_in[2];
    const float* W    = (const float*)d_in[3];
    const float* bias = (const float*)d_in[4];
    float* out = (float*)d_out;

    sinenet_kernel<<<ROWS / WPB, 256, 0, stream>>>(x, nlf, tau, W, bias, out);
}

// Round 2
// 76.933 us; speedup vs baseline: 1.0746x; 1.0746x over previous
//
#include <hip/hip_runtime.h>
#include <math.h>

// SinenetLayerV3: per (s,b,m) row — harmonic sin/cos basis contracted with x
// over T, then [2K]->[D] matmul + bias + relu, concat relu(nlf).
//
// deg[k][t] = k*theta_t, theta_t = 2*pi*f*(t*T_WAV - tau).
// Per t: one hw v_sin/v_cos (revolutions), then Chebyshev 3-term recurrence
// over k (4 VALU ops/k vs 6 for complex rotation).
// Reduce: DISTRIBUTED butterfly — halve value count each xor step
// (32 shuffles total vs 384), masks 1,2 via DPP quad_perm (VALU pipe),
// then v_readlane broadcast of the 32 wave-uniform sums (no LDS).

#define T_WAV_F (1.0f / 16000.0f)
#define LOG_F_MEAN_F 5.04418f
#define LOG_F_STD_F 0.358402f

constexpr int S = 16, B = 16, M = 20, T = 640, K = 16, D = 80;
constexpr int ROWS = S * B * M;       // 5120
constexpr int WPB = 4;                // waves per block (256 threads)
constexpr int TWO_K = 2 * K;          // 32
constexpr int W_STRIDE = TWO_K + 1;   // 33: bank = (d + j) % 32 -> conflict-free b32

template <int CTRL>
__device__ __forceinline__ float dpp_qperm(float x) {
    return __int_as_float(
        __builtin_amdgcn_mov_dpp(__float_as_int(x), CTRL, 0xF, 0xF, true));
}

// xor-shuffle: masks 1,2 on VALU via DPP quad_perm; others via shfl (LDS pipe)
template <int MASK>
__device__ __forceinline__ float xsh(float x) {
    if constexpr (MASK == 1)      return dpp_qperm<0xB1>(x);  // quad_perm [1,0,3,2]
    else if constexpr (MASK == 2) return dpp_qperm<0x4E>(x);  // quad_perm [2,3,0,1]
    else                          return __shfl_xor(x, MASK, 64);
}

__global__ __launch_bounds__(256) void sinenet_kernel(
    const float* __restrict__ x,    // [S,B,M,T]
    const float* __restrict__ nlf,  // [S,B,M]
    const float* __restrict__ tau,  // [S,B,M]
    const float* __restrict__ W,    // [D, 2K]
    const float* __restrict__ bias, // [D]
    float* __restrict__ out)        // [S,B, M*D + M]
{
    __shared__ float Wlds[D * W_STRIDE];
    __shared__ float blds[D];

    for (int i = threadIdx.x; i < D * TWO_K; i += 256) {
        Wlds[(i / TWO_K) * W_STRIDE + (i % TWO_K)] = W[i];
    }
    if (threadIdx.x < D) blds[threadIdx.x] = bias[threadIdx.x];
    __syncthreads();

    const int lane = threadIdx.x & 63;
    const int row  = blockIdx.x * WPB + (threadIdx.x >> 6);  // 0..5119, grid exact

    const float* __restrict__ xrow = x + (size_t)row * T;
    const float nlf_v = nlf[row];
    const float tau_v = tau[row];

    const float f     = __expf(fmaf(nlf_v, LOG_F_STD_F, LOG_F_MEAN_F));
    const float drev  = f * T_WAV_F;          // revolutions per sample
    const float drev64 = 64.0f * drev;
    float rev = fmaf((float)lane, drev, -f * tau_v);

    // v[k] = sacc[k], v[16+k] = cacc[k]
    float v[TWO_K];
    #pragma unroll
    for (int j = 0; j < TWO_K; ++j) v[j] = 0.0f;

    #pragma unroll
    for (int it = 0; it < T / 64; ++it) {     // 10 iters, coalesced stride-64
        const float xv = xrow[lane + it * 64];
        float fr, s1, c1;
        asm("v_fract_f32 %0, %1" : "=v"(fr) : "v"(rev));   // rev - floor(rev)
        asm("v_sin_f32 %0, %1" : "=v"(s1) : "v"(fr));      // sin(2*pi*fr)
        asm("v_cos_f32 %0, %1" : "=v"(c1) : "v"(fr));      // cos(2*pi*fr)
        const float tc = c1 + c1;
        // Chebyshev: s_{k+1} = 2c1*s_k - s_{k-1}; same for c. s0=0, c0=1.
        float sp = 0.0f, s = s1, cp = 1.0f, c = c1;
        #pragma unroll
        for (int k = 0; k < K; ++k) {
            v[k]     = fmaf(xv, s, v[k]);
            v[K + k] = fmaf(xv, c, v[K + k]);
            const float ns = fmaf(tc, s, -sp);
            const float nc = fmaf(tc, c, -cp);
            sp = s; s = ns; cp = c; c = nc;
        }
        rev += drev64;
    }

    // ---- distributed butterfly reduce: 32 values -> 1 per lane ----
    // step (mask m, half h): keep logical j + h*hi, partner sends that same
    // logical index; value count halves. Final: lane l holds total of value
    // V(l) = 16*b0 + 8*b1 + 4*b2 + 2*b3 + b4   (b_i = lane bit for step i).
    {
        const int l = lane;
        { const bool hi = l & 1;                  // half 16, DPP
          #pragma unroll
          for (int j = 0; j < 16; ++j) {
              const float keep = hi ? v[j + 16] : v[j];
              const float send = hi ? v[j] : v[j + 16];
              v[j] = keep + xsh<1>(send);
          } }
        { const bool hi = l & 2;                  // half 8, DPP
          #pragma unroll
          for (int j = 0; j < 8; ++j) {
              const float keep = hi ? v[j + 8] : v[j];
              const float send = hi ? v[j] : v[j + 8];
              v[j] = keep + xsh<2>(send);
          } }
        { const bool hi = l & 4;                  // half 4
          #pragma unroll
          for (int j = 0; j < 4; ++j) {
              const float keep = hi ? v[j + 4] : v[j];
              const float send = hi ? v[j] : v[j + 4];
              v[j] = keep + xsh<4>(send);
          } }
        { const bool hi = l & 8;                  // half 2
          #pragma unroll
          for (int j = 0; j < 2; ++j) {
              const float keep = hi ? v[j + 2] : v[j];
              const float send = hi ? v[j] : v[j + 2];
              v[j] = keep + xsh<8>(send);
          } }
        { const bool hi = l & 16;                 // half 1
          const float keep = hi ? v[1] : v[0];
          const float send = hi ? v[0] : v[1];
          v[0] = keep + xsh<16>(send);
        }
        v[0] += __shfl_xor(v[0], 32, 64);
    }
    const float tot = v[0];

    // broadcast: value k lives in lane bitrev5(k); readlane -> SGPR
    float sv[TWO_K];
    #pragma unroll
    for (int k = 0; k < TWO_K; ++k) {
        const int src = ((k & 1) << 4) | ((k & 2) << 2) | (k & 4) |
                        ((k & 8) >> 2) | ((k & 16) >> 4);
        sv[k] = __int_as_float(
            __builtin_amdgcn_readlane(__float_as_int(tot), src));
    }

    // epilogue: y[d] = sum_j sv[j]*W[d][j] + b[d]; relu; store
    const int sb = row / M;
    const int m  = row % M;
    float* __restrict__ orow = out + (size_t)sb * (M * D + M);

    #pragma unroll
    for (int pass = 0; pass < 2; ++pass) {
        const int d = lane + pass * 64;
        if (d < D) {
            const float* __restrict__ wr = &Wlds[d * W_STRIDE];
            float y = blds[d];
            #pragma unroll
            for (int j = 0; j < TWO_K; ++j) {
                y = fmaf(sv[j], wr[j], y);
            }
            orow[m * D + d] = fmaxf(y, 0.0f);
        }
    }
    if (lane == 0) orow[M * D + m] = fmaxf(nlf_v, 0.0f);
}

extern "C" void kernel_launch(void* const* d_in, const int* in_sizes, int n_in,
                              void* d_out, int out_size, void* d_ws, size_t ws_size,
                              hipStream_t stream) {
    const float* x    = (const float*)d_in[0];
    const float* nlf  = (const float*)d_in[1];
    const float* tau  = (const float*)d_in[2];
    const float* W    = (const float*)d_in[3];
    const float* bias = (const float*)d_in[4];
    float* out = (float*)d_out;

    sinenet_kernel<<<ROWS / WPB, 256, 0, stream>>>(x, nlf, tau, W, bias, out);
}

// Round 3
// 76.352 us; speedup vs baseline: 1.0828x; 1.0076x over previous
//
#include <hip/hip_runtime.h>
#include <math.h>

// SinenetLayerV3: per (s,b,m) row — harmonic sin/cos basis contracted with x
// over T, then [2K]->[D] matmul + bias + relu, concat relu(nlf).
//
// deg[k][t] = k*theta_t, theta_t = 2*pi*f*(t*T_WAV - tau).
// Per t: one hw v_sin/v_cos (revolutions), then Chebyshev 3-term recurrence
// over k, PACKED: (s,c) pairs in v_pk_fma_f32 (2 f32/lane/instr — the 157 TF
// fp32 path). 2 pk-FMAs per k vs 4 scalar FMAs.
// Reduce: distributed butterfly (value count halves each step); mask-1 step
// consumes the (s,c) pair split directly; masks 1,2 via DPP quad_perm (VALU
// pipe), rest via shfl; then v_readlane broadcast (no LDS round-trip).

#define T_WAV_F (1.0f / 16000.0f)
#define LOG_F_MEAN_F 5.04418f
#define LOG_F_STD_F 0.358402f

constexpr int S = 16, B = 16, M = 20, T = 640, K = 16, D = 80;
constexpr int ROWS = S * B * M;       // 5120
constexpr int WPB = 4;                // waves per block (256 threads)
constexpr int TWO_K = 2 * K;          // 32
constexpr int W_STRIDE = TWO_K + 1;   // 33: bank = (d + j) % 32 -> 2-way max (free)

typedef float f32x2 __attribute__((ext_vector_type(2)));

__device__ __forceinline__ f32x2 pk_fma(f32x2 a, f32x2 b, f32x2 c) {
    f32x2 d;
    asm("v_pk_fma_f32 %0, %1, %2, %3" : "=v"(d) : "v"(a), "v"(b), "v"(c));
    return d;
}
// d = a*b - c  (neg on src2, both halves)
__device__ __forceinline__ f32x2 pk_fma_nc(f32x2 a, f32x2 b, f32x2 c) {
    f32x2 d;
    asm("v_pk_fma_f32 %0, %1, %2, %3 neg_lo:[0,0,1] neg_hi:[0,0,1]"
        : "=v"(d) : "v"(a), "v"(b), "v"(c));
    return d;
}

template <int CTRL>
__device__ __forceinline__ float dpp_qperm(float x) {
    return __int_as_float(
        __builtin_amdgcn_mov_dpp(__float_as_int(x), CTRL, 0xF, 0xF, true));
}

template <int MASK>
__device__ __forceinline__ float xsh(float x) {
    if constexpr (MASK == 1)      return dpp_qperm<0xB1>(x);  // quad_perm [1,0,3,2]
    else if constexpr (MASK == 2) return dpp_qperm<0x4E>(x);  // quad_perm [2,3,0,1]
    else                          return __shfl_xor(x, MASK, 64);
}

__global__ __launch_bounds__(256) void sinenet_kernel(
    const float* __restrict__ x,    // [S,B,M,T]
    const float* __restrict__ nlf,  // [S,B,M]
    const float* __restrict__ tau,  // [S,B,M]
    const float* __restrict__ W,    // [D, 2K]
    const float* __restrict__ bias, // [D]
    float* __restrict__ out)        // [S,B, M*D + M]
{
    __shared__ float Wlds[D * W_STRIDE];
    __shared__ float blds[D];

    for (int i = threadIdx.x; i < D * TWO_K; i += 256) {
        Wlds[(i / TWO_K) * W_STRIDE + (i % TWO_K)] = W[i];
    }
    if (threadIdx.x < D) blds[threadIdx.x] = bias[threadIdx.x];
    __syncthreads();

    const int lane = threadIdx.x & 63;
    const int row  = blockIdx.x * WPB + (threadIdx.x >> 6);  // 0..5119, grid exact

    const float* __restrict__ xrow = x + (size_t)row * T;
    const float nlf_v = nlf[row];
    const float tau_v = tau[row];

    const float f      = __expf(fmaf(nlf_v, LOG_F_STD_F, LOG_F_MEAN_F));
    const float drev   = f * T_WAV_F;          // revolutions per sample
    const float drev64 = 64.0f * drev;
    float rev = fmaf((float)lane, drev, -f * tau_v);

    // acc2[k] = (sacc_k, cacc_k) packed pairs
    f32x2 acc2[K];
    #pragma unroll
    for (int k = 0; k < K; ++k) acc2[k] = (f32x2){0.0f, 0.0f};

    #pragma unroll
    for (int it = 0; it < T / 64; ++it) {     // 10 iters, coalesced stride-64
        const float xv = xrow[lane + it * 64];
        float fr, s1, c1;
        asm("v_fract_f32 %0, %1" : "=v"(fr) : "v"(rev));   // rev - floor(rev)
        asm("v_sin_f32 %0, %1" : "=v"(s1) : "v"(fr));      // sin(2*pi*fr)
        asm("v_cos_f32 %0, %1" : "=v"(c1) : "v"(fr));      // cos(2*pi*fr)
        const float tc = c1 + c1;
        f32x2 sc  = {s1, c1};                  // (sin kθ, cos kθ), k=1
        f32x2 scp = {0.0f, 1.0f};              // k=0
        const f32x2 tc2 = {tc, tc};
        const f32x2 xv2 = {xv, xv};
        // Chebyshev: sc_{k+1} = 2c1*sc_k - sc_{k-1}, both halves in one pk op
        #pragma unroll
        for (int k = 0; k < K; ++k) {
            acc2[k] = pk_fma(xv2, sc, acc2[k]);
            const f32x2 n = pk_fma_nc(tc2, sc, scp);
            scp = sc; sc = n;
        }
        rev += drev64;
    }

    // ---- distributed butterfly reduce: 32 values -> 1 per lane ----
    // mask-1 step consumes the pair split: v[j]=acc2[j].x (s, value j),
    // acc2[j].y (c, value j+16). Final: lane l holds total of value
    // V(l) = 16*b0 + 8*b1 + 4*b2 + 2*b3 + b4 (b_i = lane bit i).
    float v[16];
    {
        const int l = lane;
        { const bool hi = l & 1;                  // 32 -> 16, DPP
          #pragma unroll
          for (int j = 0; j < 16; ++j) {
              const float keep = hi ? acc2[j][1] : acc2[j][0];
              const float send = hi ? acc2[j][0] : acc2[j][1];
              v[j] = keep + xsh<1>(send);
          } }
        { const bool hi = l & 2;                  // 16 -> 8, DPP
          #pragma unroll
          for (int j = 0; j < 8; ++j) {
              const float keep = hi ? v[j + 8] : v[j];
              const float send = hi ? v[j] : v[j + 8];
              v[j] = keep + xsh<2>(send);
          } }
        { const bool hi = l & 4;                  // 8 -> 4
          #pragma unroll
          for (int j = 0; j < 4; ++j) {
              const float keep = hi ? v[j + 4] : v[j];
              const float send = hi ? v[j] : v[j + 4];
              v[j] = keep + xsh<4>(send);
          } }
        { const bool hi = l & 8;                  // 4 -> 2
          #pragma unroll
          for (int j = 0; j < 2; ++j) {
              const float keep = hi ? v[j + 2] : v[j];
              const float send = hi ? v[j] : v[j + 2];
              v[j] = keep + xsh<8>(send);
          } }
        { const bool hi = l & 16;                 // 2 -> 1
          const float keep = hi ? v[1] : v[0];
          const float send = hi ? v[0] : v[1];
          v[0] = keep + xsh<16>(send);
        }
        v[0] += __shfl_xor(v[0], 32, 64);
    }
    const float tot = v[0];

    // broadcast: value k lives in lane bitrev5(k); readlane -> SGPR
    float sv[TWO_K];
    #pragma unroll
    for (int k = 0; k < TWO_K; ++k) {
        const int src = ((k & 1) << 4) | ((k & 2) << 2) | (k & 4) |
                        ((k & 8) >> 2) | ((k & 16) >> 4);
        sv[k] = __int_as_float(
            __builtin_amdgcn_readlane(__float_as_int(tot), src));
    }

    // epilogue: y[d] = sum_j sv[j]*W[d][j] + b[d]; relu; store
    const int sb = row / M;
    const int m  = row % M;
    float* __restrict__ orow = out + (size_t)sb * (M * D + M);

    #pragma unroll
    for (int pass = 0; pass < 2; ++pass) {
        const int d = lane + pass * 64;
        if (d < D) {
            const float* __restrict__ wr = &Wlds[d * W_STRIDE];
            float y = blds[d];
            #pragma unroll
            for (int j = 0; j < TWO_K; ++j) {
                y = fmaf(sv[j], wr[j], y);
            }
            orow[m * D + d] = fmaxf(y, 0.0f);
        }
    }
    if (lane == 0) orow[M * D + m] = fmaxf(nlf_v, 0.0f);
}

extern "C" void kernel_launch(void* const* d_in, const int* in_sizes, int n_in,
                              void* d_out, int out_size, void* d_ws, size_t ws_size,
                              hipStream_t stream) {
    const float* x    = (const float*)d_in[0];
    const float* nlf  = (const float*)d_in[1];
    const float* tau  = (const float*)d_in[2];
    const float* W    = (const float*)d_in[3];
    const float* bias = (const float*)d_in[4];
    float* out = (float*)d_out;

    sinenet_kernel<<<ROWS / WPB, 256, 0, stream>>>(x, nlf, tau, W, bias, out);
}